// Round 2
// baseline (125.564 us; speedup 1.0000x reference)
//
#include <hip/hip_runtime.h>

// ---------------------------------------------------------------------------
// Tree_42520176230890 (fused):
//   feats = x[:, using_idx]                (gather, bf16, pre-swizzled)
//   d = sigmoid(feats @ W + b)             (bf16 MFMA, fused kernel)
//   tree expansion in-block -> out (16384, 2048) f32, no d round-trip
// ---------------------------------------------------------------------------

typedef __bf16 bf16x8 __attribute__((ext_vector_type(8)));
typedef float  f32x4  __attribute__((ext_vector_type(4)));

#define BATCH 16384
#define NLEAF 1024
#define FEAT  1024
#define OUTC  2048

__device__ __forceinline__ unsigned short f2bf(float f) {
    union { float f; unsigned int u; } c; c.f = f;
    unsigned int u = c.u;
    u += 0x7FFFu + ((u >> 16) & 1u);   // RNE
    return (unsigned short)(u >> 16);
}

__device__ __forceinline__ void load_lds16(const void* g, void* l) {
    __builtin_amdgcn_global_load_lds(
        (const __attribute__((address_space(1))) unsigned int*)g,
        (__attribute__((address_space(3))) unsigned int*)l, 16, 0, 0);
}

__device__ __forceinline__ float sigmoidf(float z) {
    return 1.0f / (1.0f + __expf(-z));
}

// --- 1. idx[l] = argmax_f feature_mask[f][l] -------------------------------
__global__ void extract_idx(const float* __restrict__ fm, int* __restrict__ idx) {
    int f = blockIdx.x;
    int t = threadIdx.x;
    if (fm[(size_t)f * NLEAF + t] > 0.5f) idx[t] = f;
}

// --- 2. Wt[n][k'] = bf16(W[k][n]), k' swizzled within each 32-k block ------
// phys k' = (k&~31) | ((((k>>3)&3) ^ (n&3))<<3) | (k&7)
__global__ __launch_bounds__(256) void transpose_w(const float* __restrict__ W,
                                                   short* __restrict__ Wt) {
    __shared__ short tile[64][65];
    int k0 = blockIdx.y * 64, n0 = blockIdx.x * 64;
#pragma unroll
    for (int i = 0; i < 16; ++i) {
        int e = i * 256 + threadIdx.x;
        int kr = e >> 6, nc = e & 63;
        tile[kr][nc] = (short)f2bf(W[(size_t)(k0 + kr) * NLEAF + n0 + nc]);
    }
    __syncthreads();
#pragma unroll
    for (int i = 0; i < 16; ++i) {
        int e = i * 256 + threadIdx.x;
        int nr = e >> 6, kc = e & 63;
        int n = n0 + nr, k = k0 + kc;
        int pk2 = (k & ~31) | (((((k >> 3) & 3) ^ (n & 3))) << 3) | (k & 7);
        Wt[(size_t)n * FEAT + pk2] = tile[kc][nr];
    }
}

// --- 3. feats[r][slot'] = bf16(x[r][idx[..]]), slot' = slot ^ (r&7) --------
__global__ __launch_bounds__(256) void gather_feats(const float* __restrict__ x,
                                                    const int* __restrict__ idx,
                                                    short* __restrict__ feats) {
    int tid = blockIdx.x * 256 + threadIdx.x;   // BATCH*128 threads
    int r    = tid >> 7;
    int slot = tid & 127;
    const float* xr = x + (size_t)r * FEAT;
    union { short s[8]; int4 v; } pk;
#pragma unroll
    for (int j = 0; j < 8; ++j) pk.s[j] = (short)f2bf(xr[idx[slot * 8 + j]]);
    *(int4*)(feats + (size_t)r * FEAT + ((slot ^ (r & 7)) << 3)) = pk.v;
}

// --- 4. fused GEMM + sigmoid + tree expansion ------------------------------
// block: 64 rows x full N=1024. 512 thr (8 waves, wave-tile 64x64, 1x8 grid).
// LDS 128 KiB: A half-panel [64][512] bf16 (64K) + B[2][512][32] bf16 (2x32K);
// reused as dsm[32][1024] f32 for expansion.
__global__ __launch_bounds__(512, 2) void fused_gemm_tree(
        const short* __restrict__ feats, const short* __restrict__ Wt,
        const float* __restrict__ bias, float* __restrict__ out) {
    __shared__ __align__(16) char smem[131072];
    short* As  = (short*)smem;                   // 64 KiB
    short* Bs0 = (short*)(smem + 65536);         // 32 KiB
    short* Bs1 = (short*)(smem + 98304);         // 32 KiB
    float (*dsm)[1024] = (float(*)[1024])smem;   // 32x1024 f32 = 128 KiB

    const int t  = threadIdx.x;
    const int l  = t & 63;
    const int w  = t >> 6;
    const int lr = l & 15, lk = l >> 4;
    const int row0 = blockIdx.x * 64;

    // bias regs: col = cc*512 + w*64 + nn*16 + lr
    float bvreg[2][4];
#pragma unroll
    for (int cc = 0; cc < 2; ++cc)
#pragma unroll
        for (int nn = 0; nn < 4; ++nn)
            bvreg[cc][nn] = bias[(cc << 9) + (w << 6) + (nn << 4) + lr];

    // B ds_read offsets (shorts): row n_local, slot lk ^ (n_local&3)
    int boff[4];
#pragma unroll
    for (int nn = 0; nn < 4; ++nn) {
        int n_local = (w << 6) + (nn << 4) + lr;
        boff[nn] = n_local * 32 + ((lk ^ (lr & 3)) << 3);
    }

    f32x4 acc[2][4][4];
#pragma unroll
    for (int cc = 0; cc < 2; ++cc)
#pragma unroll
        for (int m = 0; m < 4; ++m)
#pragma unroll
            for (int n = 0; n < 4; ++n)
#pragma unroll
                for (int r = 0; r < 4; ++r) acc[cc][m][n][r] = 0.0f;

    // ---- staging helpers --------------------------------------------------
    // A half-panel h: LDS[64][512] <- feats[row0..+64][h*512..+512] (linear;
    // feats already swizzled so ds_read XOR lands right)
    auto stageA = [&](int h) {
#pragma unroll
        for (int j = 0; j < 8; ++j) {
            int idx = j * 512 + t;            // per-lane slot16
            int row = idx >> 6, s16 = idx & 63;
            const short* src = feats + (size_t)(row0 + row) * FEAT + (h << 9) + (s16 << 3);
            load_lds16(src, As + ((j * 512 + (w << 6)) << 3));
        }
    };
    // B tile (h,c,s): LDS[512][32] <- Wt[c*512..+512][h*512+s*32..+32] (linear;
    // Wt pre-swizzled within each 32-k block)
    auto stageB = [&](int hh, int cc2, int ss, short* dst) {
#pragma unroll
        for (int j = 0; j < 4; ++j) {
            int idx = j * 512 + t;            // per-lane slot16
            int n_local = idx >> 2, sl = idx & 3;
            const short* src = Wt + (size_t)((cc2 << 9) + n_local) * FEAT
                               + (hh << 9) + (ss << 5) + (sl << 3);
            load_lds16(src, dst + ((j * 512 + (w << 6)) << 3));
        }
    };

    // ---- main loop: T = h*32 + cc*16 + s ----------------------------------
    stageA(0);
    stageB(0, 0, 0, Bs0);
    __syncthreads();

    for (int h = 0; h < 2; ++h) {
#pragma unroll
        for (int cc = 0; cc < 2; ++cc) {
            for (int s = 0; s < 16; ++s) {
                const int T = h * 32 + cc * 16 + s;
                const int nT = T + 1;
                if (nT < 64) {
                    int nh = nT >> 5, nc = (nT >> 4) & 1, ns = nT & 15;
                    stageB(nh, nc, ns, (nT & 1) ? Bs1 : Bs0);
                }
                const short* Bb = (T & 1) ? Bs1 : Bs0;
                bf16x8 av[4], bv[4];
#pragma unroll
                for (int m = 0; m < 4; ++m)
                    av[m] = *(const bf16x8*)(As + (m * 16 + lr) * 512
                             + (((s * 4 + lk) ^ (lr & 7)) << 3));
#pragma unroll
                for (int n = 0; n < 4; ++n)
                    bv[n] = *(const bf16x8*)(Bb + boff[n]);
#pragma unroll
                for (int m = 0; m < 4; ++m)
#pragma unroll
                    for (int n = 0; n < 4; ++n)
                        acc[cc][m][n] = __builtin_amdgcn_mfma_f32_16x16x32_bf16(
                            av[m], bv[n], acc[cc][m][n], 0, 0, 0);
                __syncthreads();
                if (nT == 32) { stageA(1); __syncthreads(); }
            }
        }
    }

    // ---- epilogue: 2 supergroups of 32 rows -------------------------------
#pragma unroll
    for (int sg = 0; sg < 2; ++sg) {
        __syncthreads();   // prior expansion reads done (sg1) / loop done (sg0)
        // dump d = sigmoid(acc + bias) for rows [sg*32, sg*32+32)
#pragma unroll
        for (int mm = 0; mm < 2; ++mm) {
#pragma unroll
            for (int cc = 0; cc < 2; ++cc)
#pragma unroll
                for (int nn = 0; nn < 4; ++nn) {
                    int col = (cc << 9) + (w << 6) + (nn << 4) + lr;
#pragma unroll
                    for (int rr = 0; rr < 4; ++rr) {
                        int lrow = mm * 16 + lk * 4 + rr;
                        float v = acc[cc][sg * 2 + mm][nn][rr];
                        dsm[lrow][col] = sigmoidf(v + bvreg[cc][nn]);
                    }
                }
        }
        __syncthreads();
        // expansion: wave w -> rows w*4 .. w*4+4
#pragma unroll
        for (int rr2 = 0; rr2 < 4; ++rr2) {
            const int lrow = (w << 2) + rr2;
            const float* dr = dsm[lrow];
            float* orow = out + (size_t)(row0 + sg * 32 + lrow) * OUTC;

            // levels 0..5: lane l tracks its level-5 ancestor's path product
            float p = 1.0f;
#pragma unroll
            for (int j = 0; j <= 5; ++j) {
                int idx = l >> (5 - j);
                int node = (1 << j) + (idx >> 1);
                float dv = dr[node];
                p *= (idx & 1) ? (1.0f - dv) : dv;
                if ((l & ((1 << (5 - j)) - 1)) == 0)
                    orow[(2 << j) + idx] = p;
            }
            if (l < 2) orow[l] = 1.0f;

            // L=6: k = 2l, 2l+1 ; node = 64 + l
            float d6 = dr[64 + l];
            float v6[2] = { p * d6, p * (1.0f - d6) };
            *(float2*)(orow + 128 + 2 * l) = make_float2(v6[0], v6[1]);

            // L=7: k = 4l+e ; node = 128 + 2l + (e>>1)
            float d7[2] = { dr[128 + 2 * l], dr[129 + 2 * l] };
            float v7[4];
#pragma unroll
            for (int e = 0; e < 4; ++e)
                v7[e] = v6[e >> 1] * ((e & 1) ? (1.0f - d7[e >> 1]) : d7[e >> 1]);
            *(float4*)(orow + 256 + 4 * l) = make_float4(v7[0], v7[1], v7[2], v7[3]);

            // L=8: k = 8l+e ; node = 256 + 4l + (e>>1)
            float d8[4], v8[8];
#pragma unroll
            for (int q = 0; q < 4; ++q) d8[q] = dr[256 + 4 * l + q];
#pragma unroll
            for (int e = 0; e < 8; ++e)
                v8[e] = v7[e >> 1] * ((e & 1) ? (1.0f - d8[e >> 1]) : d8[e >> 1]);
            *(float4*)(orow + 512 + 8 * l)     = make_float4(v8[0], v8[1], v8[2], v8[3]);
            *(float4*)(orow + 512 + 8 * l + 4) = make_float4(v8[4], v8[5], v8[6], v8[7]);

            // L=9: k = 16l+e ; node = 512 + 8l + (e>>1)
            float d9[8], v9[16];
#pragma unroll
            for (int q = 0; q < 8; ++q) d9[q] = dr[512 + 8 * l + q];
#pragma unroll
            for (int e = 0; e < 16; ++e)
                v9[e] = v8[e >> 1] * ((e & 1) ? (1.0f - d9[e >> 1]) : d9[e >> 1]);
#pragma unroll
            for (int q = 0; q < 4; ++q)
                *(float4*)(orow + 1024 + 16 * l + 4 * q) =
                    make_float4(v9[4*q], v9[4*q+1], v9[4*q+2], v9[4*q+3]);
        }
    }
}

// --- fallback (tiny workspace): naive fused, one row per block -------------
template <bool HAS_IDX>
__global__ __launch_bounds__(256) void fused_naive(const float* __restrict__ x,
                                                   const float* __restrict__ fm,
                                                   const float* __restrict__ W,
                                                   const float* __restrict__ bias,
                                                   const int* __restrict__ idx,
                                                   float* __restrict__ out) {
    __shared__ float fx[1024];
    __shared__ float dsm[1024];
    __shared__ float tre[2048];
    __shared__ int   idl[1024];
    const int t = threadIdx.x;
    const int row = blockIdx.x;

    if (HAS_IDX) {
        for (int k = t; k < 1024; k += 256) idl[k] = idx[k];
    } else {
        for (int k = t; k < 1024; k += 256) {
            int found = 0;
            for (int f = 0; f < 1024; ++f)
                if (fm[(size_t)f * NLEAF + k] > 0.5f) found = f;
            idl[k] = found;
        }
    }
    __syncthreads();
    const float* xr = x + (size_t)row * FEAT;
    for (int k = t; k < 1024; k += 256) fx[k] = xr[idl[k]];
    __syncthreads();

    float a0 = 0.f, a1 = 0.f, a2 = 0.f, a3 = 0.f;
    for (int k = 0; k < 1024; ++k) {
        float f = fx[k];
        const float* wrp = W + (size_t)k * NLEAF + t;
        a0 = fmaf(f, wrp[0],   a0);
        a1 = fmaf(f, wrp[256], a1);
        a2 = fmaf(f, wrp[512], a2);
        a3 = fmaf(f, wrp[768], a3);
    }
    dsm[t]       = sigmoidf(a0 + bias[t]);
    dsm[t + 256] = sigmoidf(a1 + bias[t + 256]);
    dsm[t + 512] = sigmoidf(a2 + bias[t + 512]);
    dsm[t + 768] = sigmoidf(a3 + bias[t + 768]);
    if (t < 2) tre[t] = 1.0f;
    __syncthreads();

    for (int L = 0; L < 10; ++L) {
        int n = 2 << L;
        for (int k = t; k < n; k += 256) {
            int node = (1 << L) + (k >> 1);
            float dv = dsm[node];
            tre[n + k] = tre[node] * ((k & 1) ? (1.0f - dv) : dv);
        }
        __syncthreads();
    }
    float4* orow = (float4*)(out + (size_t)row * OUTC);
    const float4* ts = (const float4*)tre;
    for (int i = t; i < 512; i += 256) orow[i] = ts[i];
}

extern "C" void kernel_launch(void* const* d_in, const int* in_sizes, int n_in,
                              void* d_out, int out_size, void* d_ws, size_t ws_size,
                              hipStream_t stream) {
    const float* x    = (const float*)d_in[0];
    const float* fm   = (const float*)d_in[1];
    const float* W    = (const float*)d_in[2];
    const float* bias = (const float*)d_in[3];
    float* out = (float*)d_out;

    const size_t IDX_B   = 4096;
    const size_t WT_B    = (size_t)NLEAF * FEAT * 2;        // 2 MiB
    const size_t FEATS_B = (size_t)BATCH * FEAT * 2;        // 32 MiB
    const size_t need = IDX_B + WT_B + FEATS_B;

    if (ws_size >= need) {
        int*   idx   = (int*)d_ws;
        short* Wt    = (short*)((char*)d_ws + IDX_B);
        short* feats = (short*)((char*)d_ws + IDX_B + WT_B);

        extract_idx<<<1024, 1024, 0, stream>>>(fm, idx);
        transpose_w<<<dim3(16, 16), 256, 0, stream>>>(W, Wt);
        gather_feats<<<BATCH * 128 / 256, 256, 0, stream>>>(x, idx, feats);
        fused_gemm_tree<<<BATCH / 64, 512, 0, stream>>>(feats, Wt, bias, out);
    } else if (ws_size >= IDX_B) {
        int* idx = (int*)d_ws;
        extract_idx<<<1024, 1024, 0, stream>>>(fm, idx);
        fused_naive<true><<<BATCH, 256, 0, stream>>>(x, fm, W, bias, idx, out);
    } else {
        fused_naive<false><<<BATCH, 256, 0, stream>>>(x, fm, W, bias, nullptr, out);
    }
}